// Round 14
// baseline (240.653 us; speedup 1.0000x reference)
//
#include <hip/hip_runtime.h>
#include <math.h>

// Problem constants (from reference)
#define BATCH   4096
#define NPUMP   4
#define NCH     100
#define NTOT    104          // NPUMP + NCH
#define RESPLEN 801

// Integrator: RK4, 40 steps of dz=1250 over [0,50000] m (calibrated R9-R13:
// absmax 1.22e-4 vs 2.11e-4 threshold; fp16-G floor is 6.1e-5).
#define NSTEPS_STR "40"
#define DZ_F   1250.0f
#define HDZ_F  625.0f
#define DZ6_F  208.33333333333334f   // dz/6

typedef float v2f __attribute__((ext_vector_type(2)));

// div-free gain entry (perturbations << fp16 ulp)
__device__ __forceinline__ float gentry(float fi, float fj, float invfj,
                                        const float* __restrict__ resp_s)
{
    float D    = fj - fi;
    float ad   = fabsf(D);
    float fidx = ad * 2.0e-11f;         // 1/DF
    int   i0   = (int)fidx;
    i0 = i0 > (RESPLEN - 2) ? (RESPLEN - 2) : i0;
    float w  = fidx - (float)i0;
    float g  = resp_s[i0] * (1.0f - w) + resp_s[i0 + 1] * w;
    g = (D < 0.0f) ? -g : g;
    float ratio = fi * invfj;
    float m  = fmaxf(1.0f, ratio);
    return g * m * 1.25e10f;            // 1/EFFECTIVE_AREA
}

__device__ __forceinline__ unsigned pack2h(float f0, float f1)
{
    _Float16 h0 = (_Float16)f0, h1 = (_Float16)f1;
    unsigned short u0, u1;
    __builtin_memcpy(&u0, &h0, 2);
    __builtin_memcpy(&u1, &h1, 2);
    return (unsigned)u0 | ((unsigned)u1 << 16);
}

// ---------------- asm text-generation macros ----------------
// TWO batch elements per wave (A and B), 2 rows/lane each.
// VGPR map (clobbers): v0-v11 = 3 b128 tile buffers (modulo pipeline),
// v12-v15 = element-A accs (row0: v12/13, row1: v14/15),
// v16-v19 = element-B accs, v20-v23 = stage powers (A0,A1,B0,B1),
// v24-v27 = k, v28-v31 = RK k-sums, v32-v35 = fp16 cvt temps. s20 = ctr.
// LDS P: element A fp16[128] @ bytes 0..255, element B @ 256..511.
#define RD0(OFF) "ds_read_b128 v[0:3], %[pr] offset:" OFF "\n\t"
#define RD1(OFF) "ds_read_b128 v[4:7], %[pr] offset:" OFF "\n\t"
#define RD2(OFF) "ds_read_b128 v[8:11], %[pr] offset:" OFF "\n\t"
#define W(N)     "s_waitcnt lgkmcnt(" N ")\n\t"

// 8 dot2 for element A, one b128 tile (4 packed dwords), rows a (row0) / b (row1)
#define DTA(J0,J1,J2,J3, R0,R1,R2,R3) \
  "v_dot2_f32_f16 v12, %[a" J0 "], " R0 ", v12\n\t" \
  "v_dot2_f32_f16 v14, %[b" J0 "], " R0 ", v14\n\t" \
  "v_dot2_f32_f16 v13, %[a" J1 "], " R1 ", v13\n\t" \
  "v_dot2_f32_f16 v15, %[b" J1 "], " R1 ", v15\n\t" \
  "v_dot2_f32_f16 v12, %[a" J2 "], " R2 ", v12\n\t" \
  "v_dot2_f32_f16 v14, %[b" J2 "], " R2 ", v14\n\t" \
  "v_dot2_f32_f16 v13, %[a" J3 "], " R3 ", v13\n\t" \
  "v_dot2_f32_f16 v15, %[b" J3 "], " R3 ", v15\n\t"

// first A tile: seed accs (-loss into acc0 of each row, 0 into acc1)
#define DTAZ(R0,R1,R2,R3) \
  "v_dot2_f32_f16 v12, %[a0], " R0 ", %[nls]\n\t" \
  "v_dot2_f32_f16 v14, %[b0], " R0 ", %[nls]\n\t" \
  "v_dot2_f32_f16 v13, %[a1], " R1 ", 0\n\t" \
  "v_dot2_f32_f16 v15, %[b1], " R1 ", 0\n\t" \
  "v_dot2_f32_f16 v12, %[a2], " R2 ", v12\n\t" \
  "v_dot2_f32_f16 v14, %[b2], " R2 ", v14\n\t" \
  "v_dot2_f32_f16 v13, %[a3], " R3 ", v13\n\t" \
  "v_dot2_f32_f16 v15, %[b3], " R3 ", v15\n\t"

// element B: rows c (row0) / d (row1), accs v16-19
#define DTB(J0,J1,J2,J3, R0,R1,R2,R3) \
  "v_dot2_f32_f16 v16, %[c" J0 "], " R0 ", v16\n\t" \
  "v_dot2_f32_f16 v18, %[d" J0 "], " R0 ", v18\n\t" \
  "v_dot2_f32_f16 v17, %[c" J1 "], " R1 ", v17\n\t" \
  "v_dot2_f32_f16 v19, %[d" J1 "], " R1 ", v19\n\t" \
  "v_dot2_f32_f16 v16, %[c" J2 "], " R2 ", v16\n\t" \
  "v_dot2_f32_f16 v18, %[d" J2 "], " R2 ", v18\n\t" \
  "v_dot2_f32_f16 v17, %[c" J3 "], " R3 ", v17\n\t" \
  "v_dot2_f32_f16 v19, %[d" J3 "], " R3 ", v19\n\t"

#define DTBZ(R0,R1,R2,R3) \
  "v_dot2_f32_f16 v16, %[c0], " R0 ", %[nls]\n\t" \
  "v_dot2_f32_f16 v18, %[d0], " R0 ", %[nls]\n\t" \
  "v_dot2_f32_f16 v17, %[c1], " R1 ", 0\n\t" \
  "v_dot2_f32_f16 v19, %[d1], " R1 ", 0\n\t" \
  "v_dot2_f32_f16 v16, %[c2], " R2 ", v16\n\t" \
  "v_dot2_f32_f16 v18, %[d2], " R2 ", v18\n\t" \
  "v_dot2_f32_f16 v17, %[c3], " R3 ", v17\n\t" \
  "v_dot2_f32_f16 v19, %[d3], " R3 ", v19\n\t"

#define KRED \
  "v_add_f32 v12, v12, v13\n\t" "v_mul_f32 v24, v12, v20\n\t" \
  "v_add_f32 v14, v14, v15\n\t" "v_mul_f32 v25, v14, v21\n\t" \
  "v_add_f32 v16, v16, v17\n\t" "v_mul_f32 v26, v16, v22\n\t" \
  "v_add_f32 v18, v18, v19\n\t" "v_mul_f32 v27, v18, v23\n\t"

// One RK stage for BOTH elements: ps -> fp16 -> LDS (4 b16 writes),
// 26 broadcast b128 reads (A/B interleaved, 3-buffer modulo pipeline),
// 208 dot2. Wave-synchronous single P buffer pair, no barriers.
#define STAGE(PSTXT, KSTXT) \
  PSTXT \
  "v_cvt_f16_f32 v32, v20\n\t" \
  "v_cvt_f16_f32 v33, v21\n\t" \
  "v_cvt_f16_f32 v34, v22\n\t" \
  "v_cvt_f16_f32 v35, v23\n\t" \
  "ds_write_b16 %[pwh], v32\n\t" \
  "ds_write_b16 %[pwh], v33 offset:128\n\t" \
  "ds_write_b16 %[pwh], v34 offset:256\n\t" \
  "ds_write_b16 %[pwh], v35 offset:384\n\t" \
  RD0("0") RD1("256") RD2("16") \
  W("2") DTAZ("v0","v1","v2","v3")                          RD0("272") \
  W("2") DTBZ("v4","v5","v6","v7")                          RD1("32")  \
  W("2") DTA("4","5","6","7","v8","v9","v10","v11")         RD2("288") \
  W("2") DTB("4","5","6","7","v0","v1","v2","v3")           RD0("48")  \
  W("2") DTA("8","9","10","11","v4","v5","v6","v7")         RD1("304") \
  W("2") DTB("8","9","10","11","v8","v9","v10","v11")       RD2("64")  \
  W("2") DTA("12","13","14","15","v0","v1","v2","v3")       RD0("320") \
  W("2") DTB("12","13","14","15","v4","v5","v6","v7")       RD1("80")  \
  W("2") DTA("16","17","18","19","v8","v9","v10","v11")     RD2("336") \
  W("2") DTB("16","17","18","19","v0","v1","v2","v3")       RD0("96")  \
  W("2") DTA("20","21","22","23","v4","v5","v6","v7")       RD1("352") \
  W("2") DTB("20","21","22","23","v8","v9","v10","v11")     RD2("112") \
  W("2") DTA("24","25","26","27","v0","v1","v2","v3")       RD0("368") \
  W("2") DTB("24","25","26","27","v4","v5","v6","v7")       RD1("128") \
  W("2") DTA("28","29","30","31","v8","v9","v10","v11")     RD2("384") \
  W("2") DTB("28","29","30","31","v0","v1","v2","v3")       RD0("144") \
  W("2") DTA("32","33","34","35","v4","v5","v6","v7")       RD1("400") \
  W("2") DTB("32","33","34","35","v8","v9","v10","v11")     RD2("160") \
  W("2") DTA("36","37","38","39","v0","v1","v2","v3")       RD0("416") \
  W("2") DTB("36","37","38","39","v4","v5","v6","v7")       RD1("176") \
  W("2") DTA("40","41","42","43","v8","v9","v10","v11")     RD2("432") \
  W("2") DTB("40","41","42","43","v0","v1","v2","v3")       RD0("192") \
  W("2") DTA("44","45","46","47","v4","v5","v6","v7")       RD1("448") \
  W("2") DTB("44","45","46","47","v8","v9","v10","v11")     \
  W("1") DTA("48","49","50","51","v0","v1","v2","v3")       \
  W("0") DTB("48","49","50","51","v4","v5","v6","v7")       \
  KRED KSTXT

#define PS1 "v_mov_b32 v20, %[pA0]\n\t" "v_mov_b32 v21, %[pA1]\n\t" \
            "v_mov_b32 v22, %[pB0]\n\t" "v_mov_b32 v23, %[pB1]\n\t"
#define PS2 "v_fma_f32 v20, %[hdz], v24, %[pA0]\n\t" \
            "v_fma_f32 v21, %[hdz], v25, %[pA1]\n\t" \
            "v_fma_f32 v22, %[hdz], v26, %[pB0]\n\t" \
            "v_fma_f32 v23, %[hdz], v27, %[pB1]\n\t"
#define PS4 "v_fma_f32 v20, %[dz], v24, %[pA0]\n\t" \
            "v_fma_f32 v21, %[dz], v25, %[pA1]\n\t" \
            "v_fma_f32 v22, %[dz], v26, %[pB0]\n\t" \
            "v_fma_f32 v23, %[dz], v27, %[pB1]\n\t"

#define KS1 "v_mov_b32 v28, v24\n\t" "v_mov_b32 v29, v25\n\t" \
            "v_mov_b32 v30, v26\n\t" "v_mov_b32 v31, v27\n\t"
#define KS2 "v_fmac_f32 v28, 2.0, v24\n\t" "v_fmac_f32 v29, 2.0, v25\n\t" \
            "v_fmac_f32 v30, 2.0, v26\n\t" "v_fmac_f32 v31, 2.0, v27\n\t"
#define KS4 "v_add_f32 v28, v28, v24\n\t" "v_add_f32 v29, v29, v25\n\t" \
            "v_add_f32 v30, v30, v26\n\t" "v_add_f32 v31, v31, v27\n\t"

#define GBA(m) ,[a##m]"v"(uA##m),[b##m]"v"(uB##m)
#define GBC(m) ,[c##m]"v"(uC##m),[d##m]"v"(uD##m)

// 64 threads = 1 wave per block; TWO batch elements per wave (2b, 2b+1).
// G: 208 packed fp16 regs + ~36 clobbers + state ~= 248 regs -> 2 waves/EU,
// grid 2048 blocks = exactly one occupancy round.
__global__
__attribute__((amdgpu_flat_work_group_size(64, 64)))
__attribute__((amdgpu_waves_per_eu(2, 2)))
void raman_kernel(
    const float* __restrict__ x,        // (BATCH, 8)
    const float* __restrict__ resp,     // (801,)
    const float* __restrict__ sigwl,    // (100,)
    float* __restrict__ out)            // (BATCH, 100)
{
    // Dynamic LDS: P(A) fp16 @ bytes 0..255, P(B) @ 256..511,
    // frA @ float 128, frB @ 256, invA @ 384, invB @ 512, resp @ 640
    extern __shared__ float smem[];
    float* frA_s  = smem + 128;
    float* frB_s  = smem + 256;
    float* invA_s = smem + 384;
    float* invB_s = smem + 512;
    float* resp_s = smem + 640;

    const int b0   = blockIdx.x * 2;
    const int b1   = b0 + 1;
    const int lane = threadIdx.x;       // 0..63

    for (int i = lane; i < RESPLEN; i += 64) resp_s[i] = resp[i];

    const float* xA = x + b0 * 8;
    const float* xB = x + b1 * 8;

    {
        const float invC0 = 3.3356409519815204e-09f;   // 1/299792458
        float lamA0 = (lane < NPUMP) ? xA[lane] : sigwl[lane - NPUMP];
        float lamB0 = (lane < NPUMP) ? xB[lane] : sigwl[lane - NPUMP];
        frA_s[lane]  = 299792458.0f / lamA0;
        invA_s[lane] = lamA0 * invC0;
        frB_s[lane]  = 299792458.0f / lamB0;
        invB_s[lane] = lamB0 * invC0;
        int r1 = 64 + lane;
        float lam1 = (r1 < NTOT) ? sigwl[r1 - NPUMP] : 1.0f;  // pad: finite
        frA_s[r1]  = 299792458.0f / lam1;
        invA_s[r1] = lam1 * invC0;
        frB_s[r1]  = 299792458.0f / lam1;
        invB_s[r1] = lam1 * invC0;
    }
    __syncthreads();

    // initial powers (per element): pumps |pw|, signals 1e-3, pad rows 0
    float pA0 = (lane < NPUMP) ? fabsf(xA[NPUMP + lane]) : 0.001f;
    float pB0 = (lane < NPUMP) ? fabsf(xB[NPUMP + lane]) : 0.001f;
    float pA1 = (lane < NTOT - 64) ? 0.001f : 0.0f;
    float pB1 = (lane < NTOT - 64) ? 0.001f : 0.0f;

    // ---- G: 4 row-sets x 52 packed fp16 regs (A rows a/b, B rows c/d) ----
    unsigned uA0,uA1,uA2,uA3,uA4,uA5,uA6,uA7,uA8,uA9,uA10,uA11,uA12,uA13,
             uA14,uA15,uA16,uA17,uA18,uA19,uA20,uA21,uA22,uA23,uA24,uA25,
             uA26,uA27,uA28,uA29,uA30,uA31,uA32,uA33,uA34,uA35,uA36,uA37,
             uA38,uA39,uA40,uA41,uA42,uA43,uA44,uA45,uA46,uA47,uA48,uA49,
             uA50,uA51;
    unsigned uB0,uB1,uB2,uB3,uB4,uB5,uB6,uB7,uB8,uB9,uB10,uB11,uB12,uB13,
             uB14,uB15,uB16,uB17,uB18,uB19,uB20,uB21,uB22,uB23,uB24,uB25,
             uB26,uB27,uB28,uB29,uB30,uB31,uB32,uB33,uB34,uB35,uB36,uB37,
             uB38,uB39,uB40,uB41,uB42,uB43,uB44,uB45,uB46,uB47,uB48,uB49,
             uB50,uB51;
    unsigned uC0,uC1,uC2,uC3,uC4,uC5,uC6,uC7,uC8,uC9,uC10,uC11,uC12,uC13,
             uC14,uC15,uC16,uC17,uC18,uC19,uC20,uC21,uC22,uC23,uC24,uC25,
             uC26,uC27,uC28,uC29,uC30,uC31,uC32,uC33,uC34,uC35,uC36,uC37,
             uC38,uC39,uC40,uC41,uC42,uC43,uC44,uC45,uC46,uC47,uC48,uC49,
             uC50,uC51;
    unsigned uD0,uD1,uD2,uD3,uD4,uD5,uD6,uD7,uD8,uD9,uD10,uD11,uD12,uD13,
             uD14,uD15,uD16,uD17,uD18,uD19,uD20,uD21,uD22,uD23,uD24,uD25,
             uD26,uD27,uD28,uD29,uD30,uD31,uD32,uD33,uD34,uD35,uD36,uD37,
             uD38,uD39,uD40,uD41,uD42,uD43,uD44,uD45,uD46,uD47,uD48,uD49,
             uD50,uD51;
    {
        const float fiA0 = frA_s[lane];
        const float fiA1 = frA_s[64 + lane];
        const float fiB0 = frB_s[lane];
        const float fiB1 = frB_s[64 + lane];
        const v2f* fvA = (const v2f*)frA_s;
        const v2f* ivA = (const v2f*)invA_s;
        const v2f* fvB = (const v2f*)frB_s;
        const v2f* ivB = (const v2f*)invB_s;
#define BGP(m) { v2f fj_, iv_;                                                \
        fj_ = fvA[m]; iv_ = ivA[m];                                           \
        uA##m = pack2h(gentry(fiA0, fj_.x, iv_.x, resp_s),                    \
                       gentry(fiA0, fj_.y, iv_.y, resp_s));                   \
        uB##m = pack2h(gentry(fiA1, fj_.x, iv_.x, resp_s),                    \
                       gentry(fiA1, fj_.y, iv_.y, resp_s));                   \
        fj_ = fvB[m]; iv_ = ivB[m];                                           \
        uC##m = pack2h(gentry(fiB0, fj_.x, iv_.x, resp_s),                    \
                       gentry(fiB0, fj_.y, iv_.y, resp_s));                   \
        uD##m = pack2h(gentry(fiB1, fj_.x, iv_.x, resp_s),                    \
                       gentry(fiB1, fj_.y, iv_.y, resp_s)); }
        BGP(0)  BGP(1)  BGP(2)  BGP(3)  BGP(4)  BGP(5)  BGP(6)  BGP(7)
        BGP(8)  BGP(9)  BGP(10) BGP(11) BGP(12) BGP(13) BGP(14) BGP(15)
        BGP(16) BGP(17) BGP(18) BGP(19) BGP(20) BGP(21) BGP(22) BGP(23)
        BGP(24) BGP(25) BGP(26) BGP(27) BGP(28) BGP(29) BGP(30) BGP(31)
        BGP(32) BGP(33) BGP(34) BGP(35) BGP(36) BGP(37) BGP(38) BGP(39)
        BGP(40) BGP(41) BGP(42) BGP(43) BGP(44) BGP(45) BGP(46) BGP(47)
        BGP(48) BGP(49) BGP(50) BGP(51)
#undef BGP
    }

    const int pwh_off = lane * 2;       // byte offset of fp16 P_A[lane]
    const int pr0     = 0;              // read base
    const float nlossf = -(0.0002f * 0.23025850929940458f);
    const float hdzf = HDZ_F, dzf = DZ_F, dz6f = DZ6_F;

    asm volatile(
        "s_mov_b32 s20, " NSTEPS_STR "\n\t"
        "Lrk_%=:\n\t"
        STAGE(PS1, KS1)
        STAGE(PS2, KS2)
        STAGE(PS2, KS2)
        STAGE(PS4, KS4)
        "v_fmac_f32 %[pA0], %[dz6], v28\n\t"
        "v_fmac_f32 %[pA1], %[dz6], v29\n\t"
        "v_fmac_f32 %[pB0], %[dz6], v30\n\t"
        "v_fmac_f32 %[pB1], %[dz6], v31\n\t"
        "s_sub_u32 s20, s20, 1\n\t"
        "s_cmp_lg_u32 s20, 0\n\t"
        "s_cbranch_scc1 Lrk_%=\n\t"
        : [pA0]"+v"(pA0), [pA1]"+v"(pA1), [pB0]"+v"(pB0), [pB1]"+v"(pB1)
        : [pwh]"v"(pwh_off), [pr]"v"(pr0), [nls]"s"(nlossf),
          [hdz]"s"(hdzf), [dz]"s"(dzf), [dz6]"s"(dz6f)
          GBA(0)  GBA(1)  GBA(2)  GBA(3)  GBA(4)  GBA(5)  GBA(6)  GBA(7)
          GBA(8)  GBA(9)  GBA(10) GBA(11) GBA(12) GBA(13) GBA(14) GBA(15)
          GBA(16) GBA(17) GBA(18) GBA(19) GBA(20) GBA(21) GBA(22) GBA(23)
          GBA(24) GBA(25) GBA(26) GBA(27) GBA(28) GBA(29) GBA(30) GBA(31)
          GBA(32) GBA(33) GBA(34) GBA(35) GBA(36) GBA(37) GBA(38) GBA(39)
          GBA(40) GBA(41) GBA(42) GBA(43) GBA(44) GBA(45) GBA(46) GBA(47)
          GBA(48) GBA(49) GBA(50) GBA(51)
          GBC(0)  GBC(1)  GBC(2)  GBC(3)  GBC(4)  GBC(5)  GBC(6)  GBC(7)
          GBC(8)  GBC(9)  GBC(10) GBC(11) GBC(12) GBC(13) GBC(14) GBC(15)
          GBC(16) GBC(17) GBC(18) GBC(19) GBC(20) GBC(21) GBC(22) GBC(23)
          GBC(24) GBC(25) GBC(26) GBC(27) GBC(28) GBC(29) GBC(30) GBC(31)
          GBC(32) GBC(33) GBC(34) GBC(35) GBC(36) GBC(37) GBC(38) GBC(39)
          GBC(40) GBC(41) GBC(42) GBC(43) GBC(44) GBC(45) GBC(46) GBC(47)
          GBC(48) GBC(49) GBC(50) GBC(51)
        : "v0","v1","v2","v3","v4","v5","v6","v7","v8","v9","v10","v11",
          "v12","v13","v14","v15","v16","v17","v18","v19","v20","v21",
          "v22","v23","v24","v25","v26","v27","v28","v29","v30","v31",
          "v32","v33","v34","v35",
          "s20","scc","memory");

    // rows NPUMP..NTOT-1 -> (BATCH, 100), both elements
    if (lane >= NPUMP) {
        out[b0 * NCH + (lane - NPUMP)] = pA0;
        out[b1 * NCH + (lane - NPUMP)] = pB0;
    }
    if (lane < NTOT - 64) {
        out[b0 * NCH + (60 + lane)] = pA1;
        out[b1 * NCH + (60 + lane)] = pB1;
    }
}

extern "C" void kernel_launch(void* const* d_in, const int* in_sizes, int n_in,
                              void* d_out, int out_size, void* d_ws, size_t ws_size,
                              hipStream_t stream)
{
    const float* x     = (const float*)d_in[0];
    const float* resp  = (const float*)d_in[1];
    const float* sigwl = (const float*)d_in[2];
    float* out = (float*)d_out;
    // dynamic LDS: 128 (P fp16 x256, two buffers) + 4x128 (fr/inv A,B)
    // + 801 (resp) floats = 640 + 801
    raman_kernel<<<BATCH / 2, 64, (640 + RESPLEN) * 4, stream>>>(x, resp, sigwl, out);
}